// Round 25
// baseline (289.092 us; speedup 1.0000x reference)
//
#include <hip/hip_runtime.h>
#include <hip/hip_bf16.h>
#include <stdint.h>

// Shapes
#define NS 256   // seq (attended axis)
#define NL 384   // columns
#define NC 256   // channel
#define NH 8     // heads
#define ND 32    // head dim
#define NHD 256  // NH*ND
#define NFQ 0.17677669529663687f              // 1/sqrt(32)
#define QSCALE (NFQ * 1.4426950408889634f)    // fold log2(e): softmax in exp2 domain

typedef unsigned short u16;
typedef unsigned int u32;
typedef __attribute__((ext_vector_type(8))) short short8;
typedef __attribute__((ext_vector_type(4))) float f32x4;

__device__ __forceinline__ float bf2f(u16 u) {
  union { u32 u; float f; } w; w.u = ((u32)u) << 16; return w.f;
}
__device__ __forceinline__ float lo16(u32 u) {
  union { u32 u; float f; } w; w.u = u << 16; return w.f;
}
__device__ __forceinline__ float hi16(u32 u) {
  union { u32 u; float f; } w; w.u = u & 0xffff0000u; return w.f;
}
__device__ __forceinline__ u16 f2bf_rne(float f) {
  u32 x = __float_as_uint(f);
  u32 lsb = (x >> 16) & 1u;
  x += 0x7fffu + lsb;
  return (u16)(x >> 16);
}
// HW packed convert (RNE): 2 f32 -> 1 u32 of 2 bf16 (S0 -> lo, S1 -> hi).
__device__ __forceinline__ u32 pk2(float a, float b) {
  u32 r;
  asm("v_cvt_pk_bf16_f32 %0, %1, %2" : "=v"(r) : "v"(a), "v"(b));
  return r;
}

// async global->LDS, 16B per lane (DMA; drained by vmcnt(0) before barriers)
__device__ __forceinline__ void gl_lds16(const u16* g, u16* l) {
  __builtin_amdgcn_global_load_lds(
      (const __attribute__((address_space(1))) void*)g,
      (__attribute__((address_space(3))) void*)l, 16, 0, 0);
}

template<bool F32>
__device__ __forceinline__ float ldE(const void* p, size_t i) {
  if constexpr (F32) return ((const float*)p)[i];
  else               return bf2f(((const u16*)p)[i]);
}
template<bool F32>
__device__ __forceinline__ void ld16(const void* p, size_t i, float* x) {
  if constexpr (F32) {
    const float4* q = (const float4*)((const float*)p + i);
#pragma unroll
    for (int w = 0; w < 4; ++w) {
      float4 v = q[w];
      x[4*w] = v.x; x[4*w+1] = v.y; x[4*w+2] = v.z; x[4*w+3] = v.w;
    }
  } else {
    const uint4* q = (const uint4*)((const u16*)p + i);
#pragma unroll
    for (int w = 0; w < 2; ++w) {
      uint4 v = q[w];
      u32 uu[4] = {v.x, v.y, v.z, v.w};
#pragma unroll
      for (int pk = 0; pk < 4; ++pk) {
        x[8*w + 2*pk]     = lo16(uu[pk]);
        x[8*w + 2*pk + 1] = hi16(uu[pk]);
      }
    }
  }
}

// ---------------- dtype probe ----------------
__global__ void k_probe(const u16* __restrict__ msa, int* __restrict__ flag) {
  const int t = threadIdx.x;  // 64 threads
  int cnt = 0;
#pragma unroll
  for (int i = 0; i < 4; ++i) {
    u16 v = msa[t * 4 + i];
    int e = (v >> 7) & 0xFF;
    cnt += (e >= 100 && e <= 150) ? 1 : 0;
  }
#pragma unroll
  for (int m = 1; m < 64; m <<= 1) cnt += __shfl_xor(cnt, m, 64);
  if (t == 0) *flag = (cnt < 220) ? 1 : 0;  // 1 = fp32 buffers
}

// ---------------- k_wt: transpose+cast 5 weights to bf16 wT[n][k] ----------------
__launch_bounds__(256)
__global__ void k_wt(const int* __restrict__ flag,
                     const void* __restrict__ w0, const void* __restrict__ w1,
                     const void* __restrict__ w2, const void* __restrict__ w3,
                     const void* __restrict__ w4,
                     u16* __restrict__ wT) {
  __shared__ float f[64][65];
  const int b = blockIdx.x;
  const int widx = b >> 4, tile = b & 15;
  const int k0 = (tile >> 2) * 64, n0 = (tile & 3) * 64;
  const void* src = widx == 0 ? w0 : widx == 1 ? w1 : widx == 2 ? w2 : widx == 3 ? w3 : w4;
  u16* dst = wT + widx * 65536;
  const int t = threadIdx.x;
  const bool isf32 = (*flag != 0);

  {
    const int kr = t >> 2, nc = (t & 3) * 16;
    float x[16];
    if (isf32) ld16<true >(src, (size_t)(k0 + kr) * NHD + n0 + nc, x);
    else       ld16<false>(src, (size_t)(k0 + kr) * NHD + n0 + nc, x);
#pragma unroll
    for (int i = 0; i < 16; ++i) f[kr][nc + i] = x[i];
  }
  __syncthreads();
  {
    const int nr = t >> 2, kc = (t & 3) * 16;
    u32 pk[8];
#pragma unroll
    for (int i = 0; i < 8; ++i)
      pk[i] = pk2(f[kc + 2*i][nr], f[kc + 2*i + 1][nr]);
    uint4* dp = (uint4*)(dst + (size_t)(n0 + nr) * NC + k0 + kc);
    dp[0] = make_uint4(pk[0], pk[1], pk[2], pk[3]);
    dp[1] = make_uint4(pk[4], pk[5], pk[6], pk[7]);
  }
}

// ---------------- k_ln: LayerNorm -> bf16 mhat[m][256], coalesced ----------------
__launch_bounds__(256)
__global__ void k_ln(const int* __restrict__ flag,
                     const void* __restrict__ msa,
                     const void* __restrict__ gamma_,
                     const void* __restrict__ beta_,
                     u16* __restrict__ mh) {
  const int t = threadIdx.x;
  const int row = blockIdx.x * 16 + (t >> 4);
  const int sub = t & 15;
  const bool isf32 = (*flag != 0);
  float x[16];
  if (isf32) ld16<true >(msa, (size_t)row * NC + sub * 16, x);
  else       ld16<false>(msa, (size_t)row * NC + sub * 16, x);
  float sm = 0.f, ss = 0.f;
#pragma unroll
  for (int i = 0; i < 16; ++i) { sm += x[i]; ss += x[i] * x[i]; }
#pragma unroll
  for (int msk = 1; msk < 16; msk <<= 1) {
    sm += __shfl_xor(sm, msk, 64);
    ss += __shfl_xor(ss, msk, 64);
  }
  float mu  = sm * (1.0f / NC);
  float var = fmaxf(ss * (1.0f / NC) - mu * mu, 0.0f);
  float rs  = rsqrtf(var + 1e-5f);
  float gm[16], be[16];
  if (isf32) {
    ld16<true >(gamma_, sub * 16, gm);
    ld16<true >(beta_,  sub * 16, be);
  } else {
    ld16<false>(gamma_, sub * 16, gm);
    ld16<false>(beta_,  sub * 16, be);
  }
  float y[16];
#pragma unroll
  for (int i = 0; i < 16; ++i) y[i] = (x[i] - mu) * rs * gm[i] + be[i];
  uint4* dp = (uint4*)(mh + (size_t)row * NC + sub * 16);
  dp[0] = make_uint4(pk2(y[0], y[1]),  pk2(y[2], y[3]),  pk2(y[4], y[5]),  pk2(y[6], y[7]));
  dp[1] = make_uint4(pk2(y[8], y[9]),  pk2(y[10], y[11]), pk2(y[12], y[13]), pk2(y[14], y[15]));
}

// ---------------- k_gemm<V>: 128x128-tile bf16 MFMA GEMM, 2-phase pipeline ----------------
// R24-proven structure; added __launch_bounds__(256,4): VGPR 64 and LDS
// 34.8KB both permit 4 blocks/CU (139KB LDS) but achieved occupancy was only
// ~2.6 blocks — request the full residency (pipes unsaturated: latency regime).
template<int V>
__launch_bounds__(256, 4)
__global__ void k_gemm(const int* __restrict__ flag,
                       const u16* __restrict__ Abuf,
                       const u16* __restrict__ Wbuf,
                       const void* __restrict__ bias,
                       u16* __restrict__ qb, u16* __restrict__ kb,
                       u16* __restrict__ vb, u16* __restrict__ gb,
                       void* __restrict__ outp) {
  __shared__ u16 smem[17408];   // dbuf 2x(4096+4096); epilogue Cl[128][136]
  const int t = threadIdx.x;
  const int w = t >> 6, lane = t & 63;
  const int q15 = lane & 15, g = lane >> 4;
  const int wm = w >> 1, wn = w & 1;
  int mb, nb;
  if constexpr (V == 0) {
    mb = (blockIdx.x >> 6) * 8 + (blockIdx.x & 7);  // [0,768)
    nb = (blockIdx.x >> 3) & 7;                     // [0,8)
  } else {
    mb = (blockIdx.x >> 4) * 8 + (blockIdx.x & 7);  // [0,768)
    nb = (blockIdx.x >> 3) & 1;                     // [0,2)
  }
  const int m0 = mb * 128, n0 = nb * 128;
  const bool isf32 = (*flag != 0);

  // staging geometry: per buffer per kc: A,B = 512 16B-units each = 2/thread.
  // unit j: row = j>>2 (0..127), slot = j&3; src granule k8 = slot^((row>>1)&3).
  const u16* agp[2];
  const u16* bgp[2];
  u32 ldsu[2];
#pragma unroll
  for (int u = 0; u < 2; ++u) {
    const int j = u * 256 + t;
    const int row = j >> 2;
    const int k8 = (j & 3) ^ ((row >> 1) & 3);
    ldsu[u] = (u32)j * 8;
    agp[u] = Abuf + (size_t)(m0 + row) * NC + k8 * 8;
    if constexpr (V == 0) {
      const int ng = n0 + row;  // global n 0..1023
      bgp[u] = Wbuf + (size_t)(ng >> 8) * 65536 + (size_t)(ng & 255) * NC + k8 * 8;
    } else {
      bgp[u] = Wbuf + (size_t)(n0 + row) * NC + k8 * 8;
    }
  }

  f32x4 acc[4][4];
#pragma unroll
  for (int i = 0; i < 4; ++i)
#pragma unroll
    for (int j = 0; j < 4; ++j) acc[i][j] = (f32x4){0.f, 0.f, 0.f, 0.f};

  // prologue: stage kc=0 into buf0
#pragma unroll
  for (int u = 0; u < 2; ++u) {
    gl_lds16(agp[u], smem + ldsu[u]);
    gl_lds16(bgp[u], smem + 4096 + ldsu[u]);
  }
  __syncthreads();

  for (int kc = 0; kc < 8; ++kc) {
    const int p = kc & 1;
    if (kc < 7) {  // issue next-tile DMA into the other buffer (flies under MFMA)
      const int pn = p ^ 1;
#pragma unroll
      for (int u = 0; u < 2; ++u) {
        gl_lds16(agp[u] + (kc + 1) * 32, smem + pn * 8192 + ldsu[u]);
        gl_lds16(bgp[u] + (kc + 1) * 32, smem + pn * 8192 + 4096 + ldsu[u]);
      }
    }
    const u16* A = smem + p * 8192;
    const u16* B = A + 4096;
    union { uint4 u; short8 s; } af[4], wf[4];
#pragma unroll
    for (int i = 0; i < 4; ++i) {
      const int rA = wm * 64 + i * 16 + q15;
      const int sA = g ^ ((rA >> 1) & 3);
      af[i].u = *(const uint4*)(A + (size_t)rA * 32 + sA * 8);
      const int rB = wn * 64 + i * 16 + q15;
      const int sB = g ^ ((rB >> 1) & 3);
      wf[i].u = *(const uint4*)(B + (size_t)rB * 32 + sB * 8);
    }
#pragma unroll
    for (int mi = 0; mi < 4; ++mi)
#pragma unroll
      for (int ni = 0; ni < 4; ++ni)
        acc[mi][ni] = __builtin_amdgcn_mfma_f32_16x16x32_bf16(af[mi].s, wf[ni].s,
                                                             acc[mi][ni], 0, 0, 0);
    __syncthreads();   // single drain per tile
  }

  // ---- epilogue. C-frag: col = q15 = n-local, row = 4g+r = m-local ----
  if constexpr (V == 0) {
    const int widx = n0 >> 8;
    const int nnb  = n0 & 255;
    u16* Cl = smem;                       // [128][136] bf16
#pragma unroll
    for (int ni = 0; ni < 4; ++ni) {
      const int nl = wn * 64 + ni * 16 + q15;
      float bgv = 0.f;
      if (widx == 3) bgv = isf32 ? ldE<true>(bias, nnb + nl) : ldE<false>(bias, nnb + nl);
#pragma unroll
      for (int mi = 0; mi < 4; ++mi) {
#pragma unroll
        for (int r = 0; r < 4; ++r) {
          const int ml = wm * 64 + mi * 16 + 4 * g + r;
          float v = acc[mi][ni][r];
          if (widx == 0) v *= QSCALE;
          if (widx == 3) v = 1.0f / (1.0f + __expf(-(v + bgv)));
          Cl[ml * 136 + nl] = f2bf_rne(v);
        }
      }
    }
    __syncthreads();
    u16* dst = widx == 0 ? qb : widx == 1 ? kb : widx == 2 ? vb : gb;
#pragma unroll
    for (int u = 0; u < 8; ++u) {
      const int j = u * 256 + t;
      const int lane4 = j & 3;
      const int chunk = j >> 2;
      const int ml = chunk >> 2;
      const int ncl = (chunk & 3) * 32 + lane4 * 8;
      const int nn = nnb + ncl;
      const int hh = nn >> 5, dd = nn & 31;
      const int m = m0 + ml;
      const int s = m / NL, l = m % NL;
      const size_t ob = ((size_t)(l * NH + hh) * NS + s) * ND + dd;
      *(uint4*)(dst + ob) = *(const uint4*)(Cl + ml * 136 + ncl);
    }
  } else {
#pragma unroll
    for (int mi = 0; mi < 4; ++mi) {
#pragma unroll
      for (int ni = 0; ni < 4; ++ni) {
        const int n = n0 + wn * 64 + ni * 16 + q15;
        const float bov = isf32 ? ldE<true>(bias, n) : ldE<false>(bias, n);
#pragma unroll
        for (int r = 0; r < 4; ++r) {
          const int m = m0 + wm * 64 + mi * 16 + 4 * g + r;
          const float v = acc[mi][ni][r] + bov;
          if (isf32) ((float*)outp)[(size_t)m * NC + n] = v;
          else       ((u16*)outp)[(size_t)m * NC + n] = f2bf_rne(v);
        }
      }
    }
  }
}

// ---------------- k_attn: MFMA column attention (no max-sub, no clamp) ----------------
// R24-proven structure; __launch_bounds__ raised to (256,5): LDS 32KB x 5 =
// 160KB exactly fits, VGPR 60 <= 102 -> 5 blocks/CU (was achieving ~2.8).
__launch_bounds__(256, 5)
__global__ void k_attn(const u16* __restrict__ qb,
                       const u16* __restrict__ kb,
                       const u16* __restrict__ vb,
                       const u16* __restrict__ gb,
                       u16* __restrict__ xb) {
  __shared__ u16 Ks[NS * ND];   // 16 KB, unit j: key=j>>2, k-slot (j&3)^((key>>1)&3)
  __shared__ u16 Vt[ND * NS];   // 16 KB, [d][s'] pi-permuted, slot-swizzled
  const int t = threadIdx.x;
  const int w = t >> 6;
  const int lane = t & 63;
  const int q15 = lane & 15;
  const int g = lane >> 4;
  const int bid = blockIdx.x;
  const int c = bid >> 3, h = bid & 7;
  const size_t base = (size_t)bid * (NS * ND);

  // stage K (async DMA, swizzle folded into source) and V (manual transpose).
  {
    const uint4* vg = (const uint4*)(vb + base);
#pragma unroll
    for (int i = 0; i < 4; ++i) {
      const int j = t + 256 * i;
      const int key = j >> 2;
      const int kslot = (j & 3) ^ ((key >> 1) & 3);
      gl_lds16(kb + base + (size_t)key * ND + kslot * 8, Ks + (size_t)j * 8);

      const int s = j >> 2, dp = (j & 3) * 8;
      // pi perm (HW-validated): s' bits: 0-1=s0-1, 2=s4, 3-4=s2-3, 5-7=s5-7
      const int sp = (s & 0xE0) | ((s & 12) << 1) | (((s >> 4) & 1) << 2) | (s & 3);
      const int shi = sp >> 3, slo = sp & 7;
      uint4 vv = vg[j];
      u32 wds[4] = {vv.x, vv.y, vv.z, vv.w};
#pragma unroll
      for (int p = 0; p < 4; ++p) {
        const int da = dp + 2 * p, db = da + 1;
        Vt[da * NS + ((shi ^ (da & 7) ^ (da >> 3)) * 8) + slo] = (u16)(wds[p] & 0xffff);
        Vt[db * NS + ((shi ^ (db & 7) ^ (db >> 3)) * 8) + slo] = (u16)(wds[p] >> 16);
      }
    }
  }

  // Q fragments (B-operand of swapped QK^T)
  short8 qf[4];
  const int q0w = w * 64;
#pragma unroll
  for (int it = 0; it < 4; ++it) {
    union { uint4 u; short8 s; } cv;
    cv.u = *(const uint4*)(qb + base + (size_t)(q0w + it * 16 + q15) * ND + g * 8);
    qf[it] = cv.s;
  }
  __syncthreads();  // drains gl_lds16 + manual writes

  const f32x4 zero = {0.f, 0.f, 0.f, 0.f};
  const int d0 = q15, d1 = 16 + q15;
  const int x0 = (q15 & 7) ^ (q15 >> 3);   // read swizzle for d0
  const int x1 = x0 ^ 2;                   // for d1

#pragma unroll
  for (int it = 0; it < 4; ++it) {
    // ---- QK^T (swapped): lane (q15,g) reg (jt,r) = S[key=16jt+4g+r][q=q15] ----
    f32x4 sc[16];
#pragma unroll
    for (int jt = 0; jt < 16; ++jt) {
      const int srow = jt * 16 + q15;
      const int s2 = g ^ ((srow >> 1) & 3);
      union { uint4 u; short8 s; } kf;
      kf.u = *(const uint4*)(Ks + (size_t)srow * ND + s2 * 8);
      sc[jt] = __builtin_amdgcn_mfma_f32_16x16x32_bf16(kf.s, qf[it], zero, 0, 0, 0);
    }
    // ---- fused exp2 (no max-sub, no clamp) + sum + bf16 pack ----
    float s0 = 0.f, s1 = 0.f, s2s = 0.f, s3 = 0.f;
    u32 P0[16], P1[16];
#pragma unroll
    for (int jt = 0; jt < 16; ++jt) {
      float e0 = exp2f(sc[jt][0]);
      float e1 = exp2f(sc[jt][1]);
      float e2 = exp2f(sc[jt][2]);
      float e3 = exp2f(sc[jt][3]);
      s0 += e0; s1 += e1; s2s += e2; s3 += e3;
      P0[jt] = pk2(e0, e1);
      P1[jt] = pk2(e2, e3);
    }
    float sum = (s0 + s1) + (s2s + s3);
    sum += __shfl_xor(sum, 16, 64);
    sum += __shfl_xor(sum, 32, 64);
    const float inv = 1.0f / fmaxf(sum, 1e-35f);  // for q = q15

    // ---- PV: A = own regs (pi order), B = b128 from permuted Vt ----
    f32x4 o0 = zero, o1 = zero;
#pragma unroll
    for (int kc = 0; kc < 8; ++kc) {
      union { u32 w4[4]; short8 s; } pa;
      pa.w4[0] = P0[2 * kc];     pa.w4[1] = P1[2 * kc];
      pa.w4[2] = P0[2 * kc + 1]; pa.w4[3] = P1[2 * kc + 1];
      const int sl0 = (kc * 4 + g) ^ x0;
      const int sl1 = (kc * 4 + g) ^ x1;
      union { uint4 u; short8 s; } v0, v1;
      v0.u = *(const uint4*)(Vt + (size_t)d0 * NS + sl0 * 8);
      v1.u = *(const uint4*)(Vt + (size_t)d1 * NS + sl1 * 8);
      o0 = __builtin_amdgcn_mfma_f32_16x16x32_bf16(pa.s, v0.s, o0, 0, 0, 0);
      o1 = __builtin_amdgcn_mfma_f32_16x16x32_bf16(pa.s, v1.s, o1, 0, 0, 0);
    }

    // ---- epilogue: normalize + gate + store. lane: d = q15 (+16), q = it*16+4g+r ----
    const int qrow0 = q0w + it * 16 + 4 * g;
#pragma unroll
    for (int r = 0; r < 4; ++r) {
      const int s_idx = qrow0 + r;
      const float invr = __shfl(inv, 4 * g + r, 64);  // inv lives in lane q15 == 4g+r
      float g0 = bf2f(gb[base + (size_t)s_idx * ND + q15]);
      float g1 = bf2f(gb[base + (size_t)s_idx * ND + 16 + q15]);
      const size_t off = ((size_t)s_idx * NL + c) * NHD + h * ND;
      xb[off + q15]      = f2bf_rne(o0[r] * invr * g0);
      xb[off + 16 + q15] = f2bf_rne(o1[r] * invr * g1);
    }
  }
}

extern "C" void kernel_launch(void* const* d_in, const int* in_sizes, int n_in,
                              void* d_out, int out_size, void* d_ws, size_t ws_size,
                              hipStream_t stream) {
  const void* msa    = d_in[0];
  const void* gamma_ = d_in[1];
  const void* beta_  = d_in[2];
  const void* wq     = d_in[3];
  const void* wk     = d_in[4];
  const void* wv     = d_in[5];
  const void* wg     = d_in[6];
  const void* bg     = d_in[7];
  const void* wo     = d_in[8];
  const void* bo     = d_in[9];

  const size_t NE = (size_t)NS * NL * NH * ND;  // 25,165,824 elems (= 98304*256)
  int* flag = (int*)d_ws;
  u16* wT = (u16*)((char*)d_ws + 256);          // 5 x 65536 bf16 = 640 KB
  u16* qb = wT + 5 * 65536;
  u16* kb = qb + NE;
  u16* vb = kb + NE;                            // V: linear [l,h][s][d]
  u16* gb = vb + NE;
  u16* mh = gb + NE;                            // LN output, bf16 [m][256]
  u16* xb = mh + NE;                            // attn output, bf16 [m][256]

  k_probe<<<dim3(1), dim3(64), 0, stream>>>((const u16*)msa, flag);
  k_wt<<<dim3(80), dim3(256), 0, stream>>>(flag, wq, wk, wv, wg, wo, wT);
  k_ln<<<dim3(6144), dim3(256), 0, stream>>>(flag, msa, gamma_, beta_, mh);
  k_gemm<0><<<dim3(768 * 8), dim3(256), 0, stream>>>(flag, mh, wT, bg,
                                                     qb, kb, vb, gb, nullptr);
  k_attn<<<dim3(NL * NH), dim3(256), 0, stream>>>(qb, kb, vb, gb, xb);
  k_gemm<1><<<dim3(768 * 2), dim3(256), 0, stream>>>(flag, xb, wT + 4 * 65536, bo,
                                                     nullptr, nullptr, nullptr, nullptr, d_out);
}

// Round 26
// 260.964 us; speedup vs baseline: 1.1078x; 1.1078x over previous
//
#include <hip/hip_runtime.h>
#include <hip/hip_bf16.h>
#include <stdint.h>

// Shapes
#define NS 256   // seq (attended axis)
#define NL 384   // columns
#define NC 256   // channel
#define NH 8     // heads
#define ND 32    // head dim
#define NHD 256  // NH*ND
#define NFQ 0.17677669529663687f              // 1/sqrt(32)
#define QSCALE (NFQ * 1.4426950408889634f)    // fold log2(e): softmax in exp2 domain

typedef unsigned short u16;
typedef unsigned int u32;
typedef __attribute__((ext_vector_type(8))) short short8;
typedef __attribute__((ext_vector_type(4))) float f32x4;

__device__ __forceinline__ float bf2f(u16 u) {
  union { u32 u; float f; } w; w.u = ((u32)u) << 16; return w.f;
}
__device__ __forceinline__ float lo16(u32 u) {
  union { u32 u; float f; } w; w.u = u << 16; return w.f;
}
__device__ __forceinline__ float hi16(u32 u) {
  union { u32 u; float f; } w; w.u = u & 0xffff0000u; return w.f;
}
__device__ __forceinline__ u16 f2bf_rne(float f) {
  u32 x = __float_as_uint(f);
  u32 lsb = (x >> 16) & 1u;
  x += 0x7fffu + lsb;
  return (u16)(x >> 16);
}
// HW packed convert (RNE): 2 f32 -> 1 u32 of 2 bf16 (S0 -> lo, S1 -> hi).
__device__ __forceinline__ u32 pk2(float a, float b) {
  u32 r;
  asm("v_cvt_pk_bf16_f32 %0, %1, %2" : "=v"(r) : "v"(a), "v"(b));
  return r;
}

// async global->LDS, 16B per lane (DMA; drained by vmcnt(0) before barriers)
__device__ __forceinline__ void gl_lds16(const u16* g, u16* l) {
  __builtin_amdgcn_global_load_lds(
      (const __attribute__((address_space(1))) void*)g,
      (__attribute__((address_space(3))) void*)l, 16, 0, 0);
}

template<bool F32>
__device__ __forceinline__ float ldE(const void* p, size_t i) {
  if constexpr (F32) return ((const float*)p)[i];
  else               return bf2f(((const u16*)p)[i]);
}
template<bool F32>
__device__ __forceinline__ void ld16(const void* p, size_t i, float* x) {
  if constexpr (F32) {
    const float4* q = (const float4*)((const float*)p + i);
#pragma unroll
    for (int w = 0; w < 4; ++w) {
      float4 v = q[w];
      x[4*w] = v.x; x[4*w+1] = v.y; x[4*w+2] = v.z; x[4*w+3] = v.w;
    }
  } else {
    const uint4* q = (const uint4*)((const u16*)p + i);
#pragma unroll
    for (int w = 0; w < 2; ++w) {
      uint4 v = q[w];
      u32 uu[4] = {v.x, v.y, v.z, v.w};
#pragma unroll
      for (int pk = 0; pk < 4; ++pk) {
        x[8*w + 2*pk]     = lo16(uu[pk]);
        x[8*w + 2*pk + 1] = hi16(uu[pk]);
      }
    }
  }
}

// ---------------- dtype probe ----------------
__global__ void k_probe(const u16* __restrict__ msa, int* __restrict__ flag) {
  const int t = threadIdx.x;  // 64 threads
  int cnt = 0;
#pragma unroll
  for (int i = 0; i < 4; ++i) {
    u16 v = msa[t * 4 + i];
    int e = (v >> 7) & 0xFF;
    cnt += (e >= 100 && e <= 150) ? 1 : 0;
  }
#pragma unroll
  for (int m = 1; m < 64; m <<= 1) cnt += __shfl_xor(cnt, m, 64);
  if (t == 0) *flag = (cnt < 220) ? 1 : 0;  // 1 = fp32 buffers
}

// ---------------- k_wt: transpose+cast 5 weights to bf16 wT[n][k] ----------------
__launch_bounds__(256)
__global__ void k_wt(const int* __restrict__ flag,
                     const void* __restrict__ w0, const void* __restrict__ w1,
                     const void* __restrict__ w2, const void* __restrict__ w3,
                     const void* __restrict__ w4,
                     u16* __restrict__ wT) {
  __shared__ float f[64][65];
  const int b = blockIdx.x;
  const int widx = b >> 4, tile = b & 15;
  const int k0 = (tile >> 2) * 64, n0 = (tile & 3) * 64;
  const void* src = widx == 0 ? w0 : widx == 1 ? w1 : widx == 2 ? w2 : widx == 3 ? w3 : w4;
  u16* dst = wT + widx * 65536;
  const int t = threadIdx.x;
  const bool isf32 = (*flag != 0);

  {
    const int kr = t >> 2, nc = (t & 3) * 16;
    float x[16];
    if (isf32) ld16<true >(src, (size_t)(k0 + kr) * NHD + n0 + nc, x);
    else       ld16<false>(src, (size_t)(k0 + kr) * NHD + n0 + nc, x);
#pragma unroll
    for (int i = 0; i < 16; ++i) f[kr][nc + i] = x[i];
  }
  __syncthreads();
  {
    const int nr = t >> 2, kc = (t & 3) * 16;
    u32 pk[8];
#pragma unroll
    for (int i = 0; i < 8; ++i)
      pk[i] = pk2(f[kc + 2*i][nr], f[kc + 2*i + 1][nr]);
    uint4* dp = (uint4*)(dst + (size_t)(n0 + nr) * NC + k0 + kc);
    dp[0] = make_uint4(pk[0], pk[1], pk[2], pk[3]);
    dp[1] = make_uint4(pk[4], pk[5], pk[6], pk[7]);
  }
}

// ---------------- k_ln: LayerNorm -> bf16 mhat[m][256], coalesced ----------------
__launch_bounds__(256)
__global__ void k_ln(const int* __restrict__ flag,
                     const void* __restrict__ msa,
                     const void* __restrict__ gamma_,
                     const void* __restrict__ beta_,
                     u16* __restrict__ mh) {
  const int t = threadIdx.x;
  const int row = blockIdx.x * 16 + (t >> 4);
  const int sub = t & 15;
  const bool isf32 = (*flag != 0);
  float x[16];
  if (isf32) ld16<true >(msa, (size_t)row * NC + sub * 16, x);
  else       ld16<false>(msa, (size_t)row * NC + sub * 16, x);
  float sm = 0.f, ss = 0.f;
#pragma unroll
  for (int i = 0; i < 16; ++i) { sm += x[i]; ss += x[i] * x[i]; }
#pragma unroll
  for (int msk = 1; msk < 16; msk <<= 1) {
    sm += __shfl_xor(sm, msk, 64);
    ss += __shfl_xor(ss, msk, 64);
  }
  float mu  = sm * (1.0f / NC);
  float var = fmaxf(ss * (1.0f / NC) - mu * mu, 0.0f);
  float rs  = rsqrtf(var + 1e-5f);
  float gm[16], be[16];
  if (isf32) {
    ld16<true >(gamma_, sub * 16, gm);
    ld16<true >(beta_,  sub * 16, be);
  } else {
    ld16<false>(gamma_, sub * 16, gm);
    ld16<false>(beta_,  sub * 16, be);
  }
  float y[16];
#pragma unroll
  for (int i = 0; i < 16; ++i) y[i] = (x[i] - mu) * rs * gm[i] + be[i];
  uint4* dp = (uint4*)(mh + (size_t)row * NC + sub * 16);
  dp[0] = make_uint4(pk2(y[0], y[1]),  pk2(y[2], y[3]),  pk2(y[4], y[5]),  pk2(y[6], y[7]));
  dp[1] = make_uint4(pk2(y[8], y[9]),  pk2(y[10], y[11]), pk2(y[12], y[13]), pk2(y[14], y[15]));
}

// ---------------- k_gemm<V>: 128x128-tile bf16 MFMA GEMM, 2-phase pipeline ----------------
// R24-proven (session best, 261.1us). BK=32 double-buffer; per kc: issue
// next-tile DMA into buf^1, compute current, ONE barrier. Granule swizzle
// slot^((row>>1)&3) folded into DMA source (both-sides rule).
template<int V>
__launch_bounds__(256)
__global__ void k_gemm(const int* __restrict__ flag,
                       const u16* __restrict__ Abuf,
                       const u16* __restrict__ Wbuf,
                       const void* __restrict__ bias,
                       u16* __restrict__ qb, u16* __restrict__ kb,
                       u16* __restrict__ vb, u16* __restrict__ gb,
                       void* __restrict__ outp) {
  __shared__ u16 smem[17408];   // dbuf 2x(4096+4096); epilogue Cl[128][136]
  const int t = threadIdx.x;
  const int w = t >> 6, lane = t & 63;
  const int q15 = lane & 15, g = lane >> 4;
  const int wm = w >> 1, wn = w & 1;
  int mb, nb;
  if constexpr (V == 0) {
    mb = (blockIdx.x >> 6) * 8 + (blockIdx.x & 7);  // [0,768)
    nb = (blockIdx.x >> 3) & 7;                     // [0,8)
  } else {
    mb = (blockIdx.x >> 4) * 8 + (blockIdx.x & 7);  // [0,768)
    nb = (blockIdx.x >> 3) & 1;                     // [0,2)
  }
  const int m0 = mb * 128, n0 = nb * 128;
  const bool isf32 = (*flag != 0);

  // staging geometry: per buffer per kc: A,B = 512 16B-units each = 2/thread.
  // unit j: row = j>>2 (0..127), slot = j&3; src granule k8 = slot^((row>>1)&3).
  const u16* agp[2];
  const u16* bgp[2];
  u32 ldsu[2];
#pragma unroll
  for (int u = 0; u < 2; ++u) {
    const int j = u * 256 + t;
    const int row = j >> 2;
    const int k8 = (j & 3) ^ ((row >> 1) & 3);
    ldsu[u] = (u32)j * 8;
    agp[u] = Abuf + (size_t)(m0 + row) * NC + k8 * 8;
    if constexpr (V == 0) {
      const int ng = n0 + row;  // global n 0..1023
      bgp[u] = Wbuf + (size_t)(ng >> 8) * 65536 + (size_t)(ng & 255) * NC + k8 * 8;
    } else {
      bgp[u] = Wbuf + (size_t)(n0 + row) * NC + k8 * 8;
    }
  }

  f32x4 acc[4][4];
#pragma unroll
  for (int i = 0; i < 4; ++i)
#pragma unroll
    for (int j = 0; j < 4; ++j) acc[i][j] = (f32x4){0.f, 0.f, 0.f, 0.f};

  // prologue: stage kc=0 into buf0
#pragma unroll
  for (int u = 0; u < 2; ++u) {
    gl_lds16(agp[u], smem + ldsu[u]);
    gl_lds16(bgp[u], smem + 4096 + ldsu[u]);
  }
  __syncthreads();

  for (int kc = 0; kc < 8; ++kc) {
    const int p = kc & 1;
    if (kc < 7) {  // issue next-tile DMA into the other buffer (flies under MFMA)
      const int pn = p ^ 1;
#pragma unroll
      for (int u = 0; u < 2; ++u) {
        gl_lds16(agp[u] + (kc + 1) * 32, smem + pn * 8192 + ldsu[u]);
        gl_lds16(bgp[u] + (kc + 1) * 32, smem + pn * 8192 + 4096 + ldsu[u]);
      }
    }
    const u16* A = smem + p * 8192;
    const u16* B = A + 4096;
    union { uint4 u; short8 s; } af[4], wf[4];
#pragma unroll
    for (int i = 0; i < 4; ++i) {
      const int rA = wm * 64 + i * 16 + q15;
      const int sA = g ^ ((rA >> 1) & 3);
      af[i].u = *(const uint4*)(A + (size_t)rA * 32 + sA * 8);
      const int rB = wn * 64 + i * 16 + q15;
      const int sB = g ^ ((rB >> 1) & 3);
      wf[i].u = *(const uint4*)(B + (size_t)rB * 32 + sB * 8);
    }
#pragma unroll
    for (int mi = 0; mi < 4; ++mi)
#pragma unroll
      for (int ni = 0; ni < 4; ++ni)
        acc[mi][ni] = __builtin_amdgcn_mfma_f32_16x16x32_bf16(af[mi].s, wf[ni].s,
                                                             acc[mi][ni], 0, 0, 0);
    __syncthreads();   // single drain per tile
  }

  // ---- epilogue. C-frag: col = q15 = n-local, row = 4g+r = m-local ----
  if constexpr (V == 0) {
    const int widx = n0 >> 8;
    const int nnb  = n0 & 255;
    u16* Cl = smem;                       // [128][136] bf16
#pragma unroll
    for (int ni = 0; ni < 4; ++ni) {
      const int nl = wn * 64 + ni * 16 + q15;
      float bgv = 0.f;
      if (widx == 3) bgv = isf32 ? ldE<true>(bias, nnb + nl) : ldE<false>(bias, nnb + nl);
#pragma unroll
      for (int mi = 0; mi < 4; ++mi) {
#pragma unroll
        for (int r = 0; r < 4; ++r) {
          const int ml = wm * 64 + mi * 16 + 4 * g + r;
          float v = acc[mi][ni][r];
          if (widx == 0) v *= QSCALE;
          if (widx == 3) v = 1.0f / (1.0f + __expf(-(v + bgv)));
          Cl[ml * 136 + nl] = f2bf_rne(v);
        }
      }
    }
    __syncthreads();
    u16* dst = widx == 0 ? qb : widx == 1 ? kb : widx == 2 ? vb : gb;
#pragma unroll
    for (int u = 0; u < 8; ++u) {
      const int j = u * 256 + t;
      const int lane4 = j & 3;
      const int chunk = j >> 2;
      const int ml = chunk >> 2;
      const int ncl = (chunk & 3) * 32 + lane4 * 8;
      const int nn = nnb + ncl;
      const int hh = nn >> 5, dd = nn & 31;
      const int m = m0 + ml;
      const int s = m / NL, l = m % NL;
      const size_t ob = ((size_t)(l * NH + hh) * NS + s) * ND + dd;
      *(uint4*)(dst + ob) = *(const uint4*)(Cl + ml * 136 + ncl);
    }
  } else {
#pragma unroll
    for (int mi = 0; mi < 4; ++mi) {
#pragma unroll
      for (int ni = 0; ni < 4; ++ni) {
        const int n = n0 + wn * 64 + ni * 16 + q15;
        const float bov = isf32 ? ldE<true>(bias, n) : ldE<false>(bias, n);
#pragma unroll
        for (int r = 0; r < 4; ++r) {
          const int m = m0 + wm * 64 + mi * 16 + 4 * g + r;
          const float v = acc[mi][ni][r] + bov;
          if (isf32) ((float*)outp)[(size_t)m * NC + n] = v;
          else       ((u16*)outp)[(size_t)m * NC + n] = f2bf_rne(v);
        }
      }
    }
  }
}

// ---------------- k_attn: MFMA column attention (no max-sub, no clamp) ----------------
// R24-proven (session best). (256,4): VGPR 60 at this bound was the measured
// sweet spot; (256,5) squeezed VGPR to 48 and regressed 25% (R25).
__launch_bounds__(256, 4)
__global__ void k_attn(const u16* __restrict__ qb,
                       const u16* __restrict__ kb,
                       const u16* __restrict__ vb,
                       const u16* __restrict__ gb,
                       u16* __restrict__ xb) {
  __shared__ u16 Ks[NS * ND];   // 16 KB, unit j: key=j>>2, k-slot (j&3)^((key>>1)&3)
  __shared__ u16 Vt[ND * NS];   // 16 KB, [d][s'] pi-permuted, slot-swizzled
  const int t = threadIdx.x;
  const int w = t >> 6;
  const int lane = t & 63;
  const int q15 = lane & 15;
  const int g = lane >> 4;
  const int bid = blockIdx.x;
  const int c = bid >> 3, h = bid & 7;
  const size_t base = (size_t)bid * (NS * ND);

  // stage K (async DMA, swizzle folded into source) and V (manual transpose).
  {
    const uint4* vg = (const uint4*)(vb + base);
#pragma unroll
    for (int i = 0; i < 4; ++i) {
      const int j = t + 256 * i;
      const int key = j >> 2;
      const int kslot = (j & 3) ^ ((key >> 1) & 3);
      gl_lds16(kb + base + (size_t)key * ND + kslot * 8, Ks + (size_t)j * 8);

      const int s = j >> 2, dp = (j & 3) * 8;
      // pi perm (HW-validated): s' bits: 0-1=s0-1, 2=s4, 3-4=s2-3, 5-7=s5-7
      const int sp = (s & 0xE0) | ((s & 12) << 1) | (((s >> 4) & 1) << 2) | (s & 3);
      const int shi = sp >> 3, slo = sp & 7;
      uint4 vv = vg[j];
      u32 wds[4] = {vv.x, vv.y, vv.z, vv.w};
#pragma unroll
      for (int p = 0; p < 4; ++p) {
        const int da = dp + 2 * p, db = da + 1;
        Vt[da * NS + ((shi ^ (da & 7) ^ (da >> 3)) * 8) + slo] = (u16)(wds[p] & 0xffff);
        Vt[db * NS + ((shi ^ (db & 7) ^ (db >> 3)) * 8) + slo] = (u16)(wds[p] >> 16);
      }
    }
  }

  // Q fragments (B-operand of swapped QK^T)
  short8 qf[4];
  const int q0w = w * 64;
#pragma unroll
  for (int it = 0; it < 4; ++it) {
    union { uint4 u; short8 s; } cv;
    cv.u = *(const uint4*)(qb + base + (size_t)(q0w + it * 16 + q15) * ND + g * 8);
    qf[it] = cv.s;
  }
  __syncthreads();  // drains gl_lds16 + manual writes

  const f32x4 zero = {0.f, 0.f, 0.f, 0.f};
  const int d0 = q15, d1 = 16 + q15;
  const int x0 = (q15 & 7) ^ (q15 >> 3);   // read swizzle for d0
  const int x1 = x0 ^ 2;                   // for d1

#pragma unroll
  for (int it = 0; it < 4; ++it) {
    // ---- QK^T (swapped): lane (q15,g) reg (jt,r) = S[key=16jt+4g+r][q=q15] ----
    f32x4 sc[16];
#pragma unroll
    for (int jt = 0; jt < 16; ++jt) {
      const int srow = jt * 16 + q15;
      const int s2 = g ^ ((srow >> 1) & 3);
      union { uint4 u; short8 s; } kf;
      kf.u = *(const uint4*)(Ks + (size_t)srow * ND + s2 * 8);
      sc[jt] = __builtin_amdgcn_mfma_f32_16x16x32_bf16(kf.s, qf[it], zero, 0, 0, 0);
    }
    // ---- fused exp2 (no max-sub, no clamp) + sum + bf16 pack ----
    float s0 = 0.f, s1 = 0.f, s2s = 0.f, s3 = 0.f;
    u32 P0[16], P1[16];
#pragma unroll
    for (int jt = 0; jt < 16; ++jt) {
      float e0 = exp2f(sc[jt][0]);
      float e1 = exp2f(sc[jt][1]);
      float e2 = exp2f(sc[jt][2]);
      float e3 = exp2f(sc[jt][3]);
      s0 += e0; s1 += e1; s2s += e2; s3 += e3;
      P0[jt] = pk2(e0, e1);
      P1[jt] = pk2(e2, e3);
    }
    float sum = (s0 + s1) + (s2s + s3);
    sum += __shfl_xor(sum, 16, 64);
    sum += __shfl_xor(sum, 32, 64);
    const float inv = 1.0f / fmaxf(sum, 1e-35f);  // for q = q15

    // ---- PV: A = own regs (pi order), B = b128 from permuted Vt ----
    f32x4 o0 = zero, o1 = zero;
#pragma unroll
    for (int kc = 0; kc < 8; ++kc) {
      union { u32 w4[4]; short8 s; } pa;
      pa.w4[0] = P0[2 * kc];     pa.w4[1] = P1[2 * kc];
      pa.w4[2] = P0[2 * kc + 1]; pa.w4[3] = P1[2 * kc + 1];
      const int sl0 = (kc * 4 + g) ^ x0;
      const int sl1 = (kc * 4 + g) ^ x1;
      union { uint4 u; short8 s; } v0, v1;
      v0.u = *(const uint4*)(Vt + (size_t)d0 * NS + sl0 * 8);
      v1.u = *(const uint4*)(Vt + (size_t)d1 * NS + sl1 * 8);
      o0 = __builtin_amdgcn_mfma_f32_16x16x32_bf16(pa.s, v0.s, o0, 0, 0, 0);
      o1 = __builtin_amdgcn_mfma_f32_16x16x32_bf16(pa.s, v1.s, o1, 0, 0, 0);
    }

    // ---- epilogue: normalize + gate + store. lane: d = q15 (+16), q = it*16+4g+r ----
    const int qrow0 = q0w + it * 16 + 4 * g;
#pragma unroll
    for (int r = 0; r < 4; ++r) {
      const int s_idx = qrow0 + r;
      const float invr = __shfl(inv, 4 * g + r, 64);  // inv lives in lane q15 == 4g+r
      float g0 = bf2f(gb[base + (size_t)s_idx * ND + q15]);
      float g1 = bf2f(gb[base + (size_t)s_idx * ND + 16 + q15]);
      const size_t off = ((size_t)s_idx * NL + c) * NHD + h * ND;
      xb[off + q15]      = f2bf_rne(o0[r] * invr * g0);
      xb[off + 16 + q15] = f2bf_rne(o1[r] * invr * g1);
    }
  }
}

extern "C" void kernel_launch(void* const* d_in, const int* in_sizes, int n_in,
                              void* d_out, int out_size, void* d_ws, size_t ws_size,
                              hipStream_t stream) {
  const void* msa    = d_in[0];
  const void* gamma_ = d_in[1];
  const void* beta_  = d_in[2];
  const void* wq     = d_in[3];
  const void* wk     = d_in[4];
  const void* wv     = d_in[5];
  const void* wg     = d_in[6];
  const void* bg     = d_in[7];
  const void* wo     = d_in[8];
  const void* bo     = d_in[9];

  const size_t NE = (size_t)NS * NL * NH * ND;  // 25,165,824 elems (= 98304*256)
  int* flag = (int*)d_ws;
  u16* wT = (u16*)((char*)d_ws + 256);          // 5 x 65536 bf16 = 640 KB
  u16* qb = wT + 5 * 65536;
  u16* kb = qb + NE;
  u16* vb = kb + NE;                            // V: linear [l,h][s][d]
  u16* gb = vb + NE;
  u16* mh = gb + NE;                            // LN output, bf16 [m][256]
  u16* xb = mh + NE;                            // attn output, bf16 [m][256]

  k_probe<<<dim3(1), dim3(64), 0, stream>>>((const u16*)msa, flag);
  k_wt<<<dim3(80), dim3(256), 0, stream>>>(flag, wq, wk, wv, wg, wo, wT);
  k_ln<<<dim3(6144), dim3(256), 0, stream>>>(flag, msa, gamma_, beta_, mh);
  k_gemm<0><<<dim3(768 * 8), dim3(256), 0, stream>>>(flag, mh, wT, bg,
                                                     qb, kb, vb, gb, nullptr);
  k_attn<<<dim3(NL * NH), dim3(256), 0, stream>>>(qb, kb, vb, gb, xb);
  k_gemm<1><<<dim3(768 * 2), dim3(256), 0, stream>>>(flag, xb, wT + 4 * 65536, bo,
                                                     nullptr, nullptr, nullptr, nullptr, d_out);
}

// Round 27
// 260.177 us; speedup vs baseline: 1.1111x; 1.0030x over previous
//
#include <hip/hip_runtime.h>
#include <hip/hip_bf16.h>
#include <stdint.h>

// Shapes
#define NS 256   // seq (attended axis)
#define NL 384   // columns
#define NC 256   // channel
#define NH 8     // heads
#define ND 32    // head dim
#define NHD 256  // NH*ND
#define NFQ 0.17677669529663687f              // 1/sqrt(32)
#define QSCALE (NFQ * 1.4426950408889634f)    // fold log2(e): softmax in exp2 domain

typedef unsigned short u16;
typedef unsigned int u32;
typedef __attribute__((ext_vector_type(8))) short short8;
typedef __attribute__((ext_vector_type(4))) float f32x4;

__device__ __forceinline__ float bf2f(u16 u) {
  union { u32 u; float f; } w; w.u = ((u32)u) << 16; return w.f;
}
__device__ __forceinline__ float lo16(u32 u) {
  union { u32 u; float f; } w; w.u = u << 16; return w.f;
}
__device__ __forceinline__ float hi16(u32 u) {
  union { u32 u; float f; } w; w.u = u & 0xffff0000u; return w.f;
}
// HW packed convert (RNE): 2 f32 -> 1 u32 of 2 bf16 (S0 -> lo, S1 -> hi).
__device__ __forceinline__ u32 pk2(float a, float b) {
  u32 r;
  asm("v_cvt_pk_bf16_f32 %0, %1, %2" : "=v"(r) : "v"(a), "v"(b));
  return r;
}
// Single bf16 convert via the same HW instruction (1 VALU op vs ~5 bit-twiddle).
__device__ __forceinline__ u16 f2bf_rne(float f) {
  return (u16)pk2(f, f);
}

// async global->LDS, 16B per lane (DMA; drained by vmcnt(0) before barriers)
__device__ __forceinline__ void gl_lds16(const u16* g, u16* l) {
  __builtin_amdgcn_global_load_lds(
      (const __attribute__((address_space(1))) void*)g,
      (__attribute__((address_space(3))) void*)l, 16, 0, 0);
}

template<bool F32>
__device__ __forceinline__ float ldE(const void* p, size_t i) {
  if constexpr (F32) return ((const float*)p)[i];
  else               return bf2f(((const u16*)p)[i]);
}
template<bool F32>
__device__ __forceinline__ void ld16(const void* p, size_t i, float* x) {
  if constexpr (F32) {
    const float4* q = (const float4*)((const float*)p + i);
#pragma unroll
    for (int w = 0; w < 4; ++w) {
      float4 v = q[w];
      x[4*w] = v.x; x[4*w+1] = v.y; x[4*w+2] = v.z; x[4*w+3] = v.w;
    }
  } else {
    const uint4* q = (const uint4*)((const u16*)p + i);
#pragma unroll
    for (int w = 0; w < 2; ++w) {
      uint4 v = q[w];
      u32 uu[4] = {v.x, v.y, v.z, v.w};
#pragma unroll
      for (int pk = 0; pk < 4; ++pk) {
        x[8*w + 2*pk]     = lo16(uu[pk]);
        x[8*w + 2*pk + 1] = hi16(uu[pk]);
      }
    }
  }
}

// ---------------- dtype probe ----------------
__global__ void k_probe(const u16* __restrict__ msa, int* __restrict__ flag) {
  const int t = threadIdx.x;  // 64 threads
  int cnt = 0;
#pragma unroll
  for (int i = 0; i < 4; ++i) {
    u16 v = msa[t * 4 + i];
    int e = (v >> 7) & 0xFF;
    cnt += (e >= 100 && e <= 150) ? 1 : 0;
  }
#pragma unroll
  for (int m = 1; m < 64; m <<= 1) cnt += __shfl_xor(cnt, m, 64);
  if (t == 0) *flag = (cnt < 220) ? 1 : 0;  // 1 = fp32 buffers
}

// ---------------- k_wt: transpose+cast 5 weights to bf16 wT[n][k] ----------------
__launch_bounds__(256)
__global__ void k_wt(const int* __restrict__ flag,
                     const void* __restrict__ w0, const void* __restrict__ w1,
                     const void* __restrict__ w2, const void* __restrict__ w3,
                     const void* __restrict__ w4,
                     u16* __restrict__ wT) {
  __shared__ float f[64][65];
  const int b = blockIdx.x;
  const int widx = b >> 4, tile = b & 15;
  const int k0 = (tile >> 2) * 64, n0 = (tile & 3) * 64;
  const void* src = widx == 0 ? w0 : widx == 1 ? w1 : widx == 2 ? w2 : widx == 3 ? w3 : w4;
  u16* dst = wT + widx * 65536;
  const int t = threadIdx.x;
  const bool isf32 = (*flag != 0);

  {
    const int kr = t >> 2, nc = (t & 3) * 16;
    float x[16];
    if (isf32) ld16<true >(src, (size_t)(k0 + kr) * NHD + n0 + nc, x);
    else       ld16<false>(src, (size_t)(k0 + kr) * NHD + n0 + nc, x);
#pragma unroll
    for (int i = 0; i < 16; ++i) f[kr][nc + i] = x[i];
  }
  __syncthreads();
  {
    const int nr = t >> 2, kc = (t & 3) * 16;
    u32 pk[8];
#pragma unroll
    for (int i = 0; i < 8; ++i)
      pk[i] = pk2(f[kc + 2*i][nr], f[kc + 2*i + 1][nr]);
    uint4* dp = (uint4*)(dst + (size_t)(n0 + nr) * NC + k0 + kc);
    dp[0] = make_uint4(pk[0], pk[1], pk[2], pk[3]);
    dp[1] = make_uint4(pk[4], pk[5], pk[6], pk[7]);
  }
}

// ---------------- k_ln: LayerNorm -> bf16 mhat[m][256], coalesced ----------------
__launch_bounds__(256)
__global__ void k_ln(const int* __restrict__ flag,
                     const void* __restrict__ msa,
                     const void* __restrict__ gamma_,
                     const void* __restrict__ beta_,
                     u16* __restrict__ mh) {
  const int t = threadIdx.x;
  const int row = blockIdx.x * 16 + (t >> 4);
  const int sub = t & 15;
  const bool isf32 = (*flag != 0);
  float x[16];
  if (isf32) ld16<true >(msa, (size_t)row * NC + sub * 16, x);
  else       ld16<false>(msa, (size_t)row * NC + sub * 16, x);
  float sm = 0.f, ss = 0.f;
#pragma unroll
  for (int i = 0; i < 16; ++i) { sm += x[i]; ss += x[i] * x[i]; }
#pragma unroll
  for (int msk = 1; msk < 16; msk <<= 1) {
    sm += __shfl_xor(sm, msk, 64);
    ss += __shfl_xor(ss, msk, 64);
  }
  float mu  = sm * (1.0f / NC);
  float var = fmaxf(ss * (1.0f / NC) - mu * mu, 0.0f);
  float rs  = rsqrtf(var + 1e-5f);
  float gm[16], be[16];
  if (isf32) {
    ld16<true >(gamma_, sub * 16, gm);
    ld16<true >(beta_,  sub * 16, be);
  } else {
    ld16<false>(gamma_, sub * 16, gm);
    ld16<false>(beta_,  sub * 16, be);
  }
  float y[16];
#pragma unroll
  for (int i = 0; i < 16; ++i) y[i] = (x[i] - mu) * rs * gm[i] + be[i];
  uint4* dp = (uint4*)(mh + (size_t)row * NC + sub * 16);
  dp[0] = make_uint4(pk2(y[0], y[1]),  pk2(y[2], y[3]),  pk2(y[4], y[5]),  pk2(y[6], y[7]));
  dp[1] = make_uint4(pk2(y[8], y[9]),  pk2(y[10], y[11]), pk2(y[12], y[13]), pk2(y[14], y[15]));
}

// ---------------- k_gemm<V>: 128x128-tile bf16 MFMA GEMM, 2-phase pipeline ----------------
// R24/R26-proven structure (session best 261us). Only change: epilogue bf16
// converts now use HW v_cvt_pk_bf16_f32 (f2bf_rne via pk2; ~5 VALU -> 1).
template<int V>
__launch_bounds__(256)
__global__ void k_gemm(const int* __restrict__ flag,
                       const u16* __restrict__ Abuf,
                       const u16* __restrict__ Wbuf,
                       const void* __restrict__ bias,
                       u16* __restrict__ qb, u16* __restrict__ kb,
                       u16* __restrict__ vb, u16* __restrict__ gb,
                       void* __restrict__ outp) {
  __shared__ u16 smem[17408];   // dbuf 2x(4096+4096); epilogue Cl[128][136]
  const int t = threadIdx.x;
  const int w = t >> 6, lane = t & 63;
  const int q15 = lane & 15, g = lane >> 4;
  const int wm = w >> 1, wn = w & 1;
  int mb, nb;
  if constexpr (V == 0) {
    mb = (blockIdx.x >> 6) * 8 + (blockIdx.x & 7);  // [0,768)
    nb = (blockIdx.x >> 3) & 7;                     // [0,8)
  } else {
    mb = (blockIdx.x >> 4) * 8 + (blockIdx.x & 7);  // [0,768)
    nb = (blockIdx.x >> 3) & 1;                     // [0,2)
  }
  const int m0 = mb * 128, n0 = nb * 128;
  const bool isf32 = (*flag != 0);

  // staging geometry: per buffer per kc: A,B = 512 16B-units each = 2/thread.
  // unit j: row = j>>2 (0..127), slot = j&3; src granule k8 = slot^((row>>1)&3).
  const u16* agp[2];
  const u16* bgp[2];
  u32 ldsu[2];
#pragma unroll
  for (int u = 0; u < 2; ++u) {
    const int j = u * 256 + t;
    const int row = j >> 2;
    const int k8 = (j & 3) ^ ((row >> 1) & 3);
    ldsu[u] = (u32)j * 8;
    agp[u] = Abuf + (size_t)(m0 + row) * NC + k8 * 8;
    if constexpr (V == 0) {
      const int ng = n0 + row;  // global n 0..1023
      bgp[u] = Wbuf + (size_t)(ng >> 8) * 65536 + (size_t)(ng & 255) * NC + k8 * 8;
    } else {
      bgp[u] = Wbuf + (size_t)(n0 + row) * NC + k8 * 8;
    }
  }

  f32x4 acc[4][4];
#pragma unroll
  for (int i = 0; i < 4; ++i)
#pragma unroll
    for (int j = 0; j < 4; ++j) acc[i][j] = (f32x4){0.f, 0.f, 0.f, 0.f};

  // prologue: stage kc=0 into buf0
#pragma unroll
  for (int u = 0; u < 2; ++u) {
    gl_lds16(agp[u], smem + ldsu[u]);
    gl_lds16(bgp[u], smem + 4096 + ldsu[u]);
  }
  __syncthreads();

  for (int kc = 0; kc < 8; ++kc) {
    const int p = kc & 1;
    if (kc < 7) {  // issue next-tile DMA into the other buffer (flies under MFMA)
      const int pn = p ^ 1;
#pragma unroll
      for (int u = 0; u < 2; ++u) {
        gl_lds16(agp[u] + (kc + 1) * 32, smem + pn * 8192 + ldsu[u]);
        gl_lds16(bgp[u] + (kc + 1) * 32, smem + pn * 8192 + 4096 + ldsu[u]);
      }
    }
    const u16* A = smem + p * 8192;
    const u16* B = A + 4096;
    union { uint4 u; short8 s; } af[4], wf[4];
#pragma unroll
    for (int i = 0; i < 4; ++i) {
      const int rA = wm * 64 + i * 16 + q15;
      const int sA = g ^ ((rA >> 1) & 3);
      af[i].u = *(const uint4*)(A + (size_t)rA * 32 + sA * 8);
      const int rB = wn * 64 + i * 16 + q15;
      const int sB = g ^ ((rB >> 1) & 3);
      wf[i].u = *(const uint4*)(B + (size_t)rB * 32 + sB * 8);
    }
#pragma unroll
    for (int mi = 0; mi < 4; ++mi)
#pragma unroll
      for (int ni = 0; ni < 4; ++ni)
        acc[mi][ni] = __builtin_amdgcn_mfma_f32_16x16x32_bf16(af[mi].s, wf[ni].s,
                                                             acc[mi][ni], 0, 0, 0);
    __syncthreads();   // single drain per tile
  }

  // ---- epilogue. C-frag: col = q15 = n-local, row = 4g+r = m-local ----
  if constexpr (V == 0) {
    const int widx = n0 >> 8;
    const int nnb  = n0 & 255;
    u16* Cl = smem;                       // [128][136] bf16
#pragma unroll
    for (int ni = 0; ni < 4; ++ni) {
      const int nl = wn * 64 + ni * 16 + q15;
      float bgv = 0.f;
      if (widx == 3) bgv = isf32 ? ldE<true>(bias, nnb + nl) : ldE<false>(bias, nnb + nl);
#pragma unroll
      for (int mi = 0; mi < 4; ++mi) {
#pragma unroll
        for (int r = 0; r < 4; ++r) {
          const int ml = wm * 64 + mi * 16 + 4 * g + r;
          float v = acc[mi][ni][r];
          if (widx == 0) v *= QSCALE;
          if (widx == 3) v = 1.0f / (1.0f + __expf(-(v + bgv)));
          Cl[ml * 136 + nl] = f2bf_rne(v);   // HW cvt (1 op)
        }
      }
    }
    __syncthreads();
    u16* dst = widx == 0 ? qb : widx == 1 ? kb : widx == 2 ? vb : gb;
#pragma unroll
    for (int u = 0; u < 8; ++u) {
      const int j = u * 256 + t;
      const int lane4 = j & 3;
      const int chunk = j >> 2;
      const int ml = chunk >> 2;
      const int ncl = (chunk & 3) * 32 + lane4 * 8;
      const int nn = nnb + ncl;
      const int hh = nn >> 5, dd = nn & 31;
      const int m = m0 + ml;
      const int s = m / NL, l = m % NL;
      const size_t ob = ((size_t)(l * NH + hh) * NS + s) * ND + dd;
      *(uint4*)(dst + ob) = *(const uint4*)(Cl + ml * 136 + ncl);
    }
  } else {
#pragma unroll
    for (int mi = 0; mi < 4; ++mi) {
#pragma unroll
      for (int ni = 0; ni < 4; ++ni) {
        const int n = n0 + wn * 64 + ni * 16 + q15;
        const float bov = isf32 ? ldE<true>(bias, n) : ldE<false>(bias, n);
#pragma unroll
        for (int r = 0; r < 4; ++r) {
          const int m = m0 + wm * 64 + mi * 16 + 4 * g + r;
          const float v = acc[mi][ni][r] + bov;
          if (isf32) ((float*)outp)[(size_t)m * NC + n] = v;
          else       ((u16*)outp)[(size_t)m * NC + n] = f2bf_rne(v);
        }
      }
    }
  }
}

// ---------------- k_attn: MFMA column attention (no max-sub, no clamp) ----------------
// R24/R26-proven structure. Epilogue now converts both outputs of each r with
// ONE v_cvt_pk_bf16_f32 (o0 -> lo, o1 -> hi) instead of two software cvts.
__launch_bounds__(256, 4)
__global__ void k_attn(const u16* __restrict__ qb,
                       const u16* __restrict__ kb,
                       const u16* __restrict__ vb,
                       const u16* __restrict__ gb,
                       u16* __restrict__ xb) {
  __shared__ u16 Ks[NS * ND];   // 16 KB, unit j: key=j>>2, k-slot (j&3)^((key>>1)&3)
  __shared__ u16 Vt[ND * NS];   // 16 KB, [d][s'] pi-permuted, slot-swizzled
  const int t = threadIdx.x;
  const int w = t >> 6;
  const int lane = t & 63;
  const int q15 = lane & 15;
  const int g = lane >> 4;
  const int bid = blockIdx.x;
  const int c = bid >> 3, h = bid & 7;
  const size_t base = (size_t)bid * (NS * ND);

  // stage K (async DMA, swizzle folded into source) and V (manual transpose).
  {
    const uint4* vg = (const uint4*)(vb + base);
#pragma unroll
    for (int i = 0; i < 4; ++i) {
      const int j = t + 256 * i;
      const int key = j >> 2;
      const int kslot = (j & 3) ^ ((key >> 1) & 3);
      gl_lds16(kb + base + (size_t)key * ND + kslot * 8, Ks + (size_t)j * 8);

      const int s = j >> 2, dp = (j & 3) * 8;
      // pi perm (HW-validated): s' bits: 0-1=s0-1, 2=s4, 3-4=s2-3, 5-7=s5-7
      const int sp = (s & 0xE0) | ((s & 12) << 1) | (((s >> 4) & 1) << 2) | (s & 3);
      const int shi = sp >> 3, slo = sp & 7;
      uint4 vv = vg[j];
      u32 wds[4] = {vv.x, vv.y, vv.z, vv.w};
#pragma unroll
      for (int p = 0; p < 4; ++p) {
        const int da = dp + 2 * p, db = da + 1;
        Vt[da * NS + ((shi ^ (da & 7) ^ (da >> 3)) * 8) + slo] = (u16)(wds[p] & 0xffff);
        Vt[db * NS + ((shi ^ (db & 7) ^ (db >> 3)) * 8) + slo] = (u16)(wds[p] >> 16);
      }
    }
  }

  // Q fragments (B-operand of swapped QK^T)
  short8 qf[4];
  const int q0w = w * 64;
#pragma unroll
  for (int it = 0; it < 4; ++it) {
    union { uint4 u; short8 s; } cv;
    cv.u = *(const uint4*)(qb + base + (size_t)(q0w + it * 16 + q15) * ND + g * 8);
    qf[it] = cv.s;
  }
  __syncthreads();  // drains gl_lds16 + manual writes

  const f32x4 zero = {0.f, 0.f, 0.f, 0.f};
  const int d0 = q15, d1 = 16 + q15;
  const int x0 = (q15 & 7) ^ (q15 >> 3);   // read swizzle for d0
  const int x1 = x0 ^ 2;                   // for d1

#pragma unroll
  for (int it = 0; it < 4; ++it) {
    // ---- QK^T (swapped): lane (q15,g) reg (jt,r) = S[key=16jt+4g+r][q=q15] ----
    f32x4 sc[16];
#pragma unroll
    for (int jt = 0; jt < 16; ++jt) {
      const int srow = jt * 16 + q15;
      const int s2 = g ^ ((srow >> 1) & 3);
      union { uint4 u; short8 s; } kf;
      kf.u = *(const uint4*)(Ks + (size_t)srow * ND + s2 * 8);
      sc[jt] = __builtin_amdgcn_mfma_f32_16x16x32_bf16(kf.s, qf[it], zero, 0, 0, 0);
    }
    // ---- fused exp2 (no max-sub, no clamp) + sum + bf16 pack ----
    float s0 = 0.f, s1 = 0.f, s2s = 0.f, s3 = 0.f;
    u32 P0[16], P1[16];
#pragma unroll
    for (int jt = 0; jt < 16; ++jt) {
      float e0 = exp2f(sc[jt][0]);
      float e1 = exp2f(sc[jt][1]);
      float e2 = exp2f(sc[jt][2]);
      float e3 = exp2f(sc[jt][3]);
      s0 += e0; s1 += e1; s2s += e2; s3 += e3;
      P0[jt] = pk2(e0, e1);
      P1[jt] = pk2(e2, e3);
    }
    float sum = (s0 + s1) + (s2s + s3);
    sum += __shfl_xor(sum, 16, 64);
    sum += __shfl_xor(sum, 32, 64);
    const float inv = 1.0f / fmaxf(sum, 1e-35f);  // for q = q15

    // ---- PV: A = own regs (pi order), B = b128 from permuted Vt ----
    f32x4 o0 = zero, o1 = zero;
#pragma unroll
    for (int kc = 0; kc < 8; ++kc) {
      union { u32 w4[4]; short8 s; } pa;
      pa.w4[0] = P0[2 * kc];     pa.w4[1] = P1[2 * kc];
      pa.w4[2] = P0[2 * kc + 1]; pa.w4[3] = P1[2 * kc + 1];
      const int sl0 = (kc * 4 + g) ^ x0;
      const int sl1 = (kc * 4 + g) ^ x1;
      union { uint4 u; short8 s; } v0, v1;
      v0.u = *(const uint4*)(Vt + (size_t)d0 * NS + sl0 * 8);
      v1.u = *(const uint4*)(Vt + (size_t)d1 * NS + sl1 * 8);
      o0 = __builtin_amdgcn_mfma_f32_16x16x32_bf16(pa.s, v0.s, o0, 0, 0, 0);
      o1 = __builtin_amdgcn_mfma_f32_16x16x32_bf16(pa.s, v1.s, o1, 0, 0, 0);
    }

    // ---- epilogue: normalize + gate + store. lane: d = q15 (+16), q = it*16+4g+r ----
    const int qrow0 = q0w + it * 16 + 4 * g;
#pragma unroll
    for (int r = 0; r < 4; ++r) {
      const int s_idx = qrow0 + r;
      const float invr = __shfl(inv, 4 * g + r, 64);  // inv lives in lane q15 == 4g+r
      float g0 = bf2f(gb[base + (size_t)s_idx * ND + q15]);
      float g1 = bf2f(gb[base + (size_t)s_idx * ND + 16 + q15]);
      const size_t off = ((size_t)s_idx * NL + c) * NHD + h * ND;
      const u32 pk = pk2(o0[r] * invr * g0, o1[r] * invr * g1);  // one HW cvt
      xb[off + q15]      = (u16)pk;
      xb[off + 16 + q15] = (u16)(pk >> 16);
    }
  }
}

extern "C" void kernel_launch(void* const* d_in, const int* in_sizes, int n_in,
                              void* d_out, int out_size, void* d_ws, size_t ws_size,
                              hipStream_t stream) {
  const void* msa    = d_in[0];
  const void* gamma_ = d_in[1];
  const void* beta_  = d_in[2];
  const void* wq     = d_in[3];
  const void* wk     = d_in[4];
  const void* wv     = d_in[5];
  const void* wg     = d_in[6];
  const void* bg     = d_in[7];
  const void* wo     = d_in[8];
  const void* bo     = d_in[9];

  const size_t NE = (size_t)NS * NL * NH * ND;  // 25,165,824 elems (= 98304*256)
  int* flag = (int*)d_ws;
  u16* wT = (u16*)((char*)d_ws + 256);          // 5 x 65536 bf16 = 640 KB
  u16* qb = wT + 5 * 65536;
  u16* kb = qb + NE;
  u16* vb = kb + NE;                            // V: linear [l,h][s][d]
  u16* gb = vb + NE;
  u16* mh = gb + NE;                            // LN output, bf16 [m][256]
  u16* xb = mh + NE;                            // attn output, bf16 [m][256]

  k_probe<<<dim3(1), dim3(64), 0, stream>>>((const u16*)msa, flag);
  k_wt<<<dim3(80), dim3(256), 0, stream>>>(flag, wq, wk, wv, wg, wo, wT);
  k_ln<<<dim3(6144), dim3(256), 0, stream>>>(flag, msa, gamma_, beta_, mh);
  k_gemm<0><<<dim3(768 * 8), dim3(256), 0, stream>>>(flag, mh, wT, bg,
                                                     qb, kb, vb, gb, nullptr);
  k_attn<<<dim3(NL * NH), dim3(256), 0, stream>>>(qb, kb, vb, gb, xb);
  k_gemm<1><<<dim3(768 * 2), dim3(256), 0, stream>>>(flag, xb, wT + 4 * 65536, bo,
                                                     nullptr, nullptr, nullptr, nullptr, d_out);
}